// Round 1
// baseline (147.856 us; speedup 1.0000x reference)
//
#include <hip/hip_runtime.h>

// Problem constants (from reference):
//   B=256, A=128, D=5, FA=256, FB=64, C=256, F = FA+FB = 320
// deg==5 (~96.2% of rows) -> output row exactly zero. Only deg<5 rows
// (~1240, of which ~98% have deg==4) need feat(320) @ W[deg](320x256).
//
// Structure (3 stream-ordered ops):
//   hipMemsetAsync  : zero 5 per-deg counters in workspace
//   scan_zero_kernel: float4-zero the whole output (write-BW bound) +
//                     compact needy rows into per-deg lists (atomics)
//   gather_mm_kernel: 4 same-deg rows per block; each W load feeds 4 FMAs
//                     (4x less L2 traffic / 4x less load-latency per row)

#define NB 256
#define NA 128
#define ND 5
#define NFA 256
#define NFB 64
#define NC 256
#define NF (NFA + NFB)   // 320
#define NROWS (NB * NA)  // 32768
#define RPB 16           // rows per scan block
#define RPC 4            // rows per compute chunk (same deg)

// ---------------------------------------------------------------------------
// Fallback: previous single-kernel version (used only if workspace too small)
// ---------------------------------------------------------------------------
__global__ __launch_bounds__(256) void ngh_kernel(
    const float* __restrict__ atoms, const float* __restrict__ bonds,
    const int* __restrict__ edges, const float* __restrict__ W,
    const float* __restrict__ bias, float* __restrict__ out)
{
    const int row = blockIdx.x;
    const int b   = row >> 7;
    const int a   = row & (NA - 1);
    const int t   = threadIdx.x;

    int e[ND];
    int deg = 0;
#pragma unroll
    for (int d = 0; d < ND; ++d) {
        e[d] = edges[row * ND + d];
        deg += (e[d] != -1) ? 1 : 0;
    }

    float* orow = out + (size_t)row * NC;
    if (deg >= ND) { orow[t] = 0.0f; return; }

    __shared__ float feat[NF];
    {
        const float* arow = atoms + ((size_t)b * NA + a) * NFA;
        float v = arow[t];
#pragma unroll
        for (int d = 0; d < ND; ++d)
            if (e[d] != -1) v += atoms[((size_t)b * NA + e[d]) * NFA + t];
        feat[t] = v;
    }
    if (t < NFB) {
        const float* brow = bonds + ((size_t)b * NA + a) * (ND * NFB);
        float v = 0.0f;
#pragma unroll
        for (int d = 0; d < ND; ++d) v += brow[d * NFB + t];
        feat[NFA + t] = v;
    }
    __syncthreads();

    const float* Wd = W + (size_t)deg * NF * NC + t;
    float acc = bias[deg * NC + t];
#pragma unroll 8
    for (int f = 0; f < NF; ++f) acc = fmaf(feat[f], Wd[(size_t)f * NC], acc);
    orow[t] = fmaxf(acc, 0.0f);
}

// ---------------------------------------------------------------------------
// Pass 1: zero-fill output + compact needy rows into per-deg lists
// ---------------------------------------------------------------------------
__global__ __launch_bounds__(256) void scan_zero_kernel(
    const int* __restrict__ edges, float* __restrict__ out,
    int* __restrict__ cnt, int* __restrict__ list)
{
    const int t  = threadIdx.x;
    const int r0 = blockIdx.x * RPB;

    // Zero RPB rows: RPB*NC/4 = 1024 float4 -> 4 per thread, fully coalesced.
    float4* dst = reinterpret_cast<float4*>(out + (size_t)r0 * NC);
    const float4 z = make_float4(0.f, 0.f, 0.f, 0.f);
#pragma unroll
    for (int k = 0; k < (RPB * NC / 4) / 256; ++k) dst[t + k * 256] = z;

    // Degree scan: one row per thread (t < 16). ~3.8% of rows get appended.
    if (t < RPB) {
        const int row = r0 + t;
        const int* er = edges + row * ND;
        int deg = 0;
#pragma unroll
        for (int d = 0; d < ND; ++d) deg += (er[d] != -1) ? 1 : 0;
        if (deg < ND) {
            const int pos = atomicAdd(&cnt[deg], 1);
            list[deg * NROWS + pos] = row;
        }
    }
}

// ---------------------------------------------------------------------------
// Pass 2: batched matvec. One chunk = RPC rows of identical deg.
// feat stored transposed in LDS ([f][r]) so the inner loop does one broadcast
// ds_read_b128 per f; each W[deg][f][c] global load feeds RPC FMAs.
// ---------------------------------------------------------------------------
__global__ __launch_bounds__(256) void gather_mm_kernel(
    const float* __restrict__ atoms, const float* __restrict__ bonds,
    const int* __restrict__ edges, const float* __restrict__ W,
    const float* __restrict__ bias, float* __restrict__ out,
    const int* __restrict__ cnt, const int* __restrict__ list)
{
    __shared__ float feat[NF * RPC];   // 320*4*4B = 5 KB
    __shared__ int rows_s[RPC];
    const int t = threadIdx.x;

    // Chunk bookkeeping (uniform across threads; ~5 uniform loads).
    int c[ND], base[ND], total = 0;
#pragma unroll
    for (int d = 0; d < ND; ++d) {
        c[d]    = cnt[d];
        base[d] = total;
        total  += (c[d] + RPC - 1) / RPC;
    }

    for (int ci = blockIdx.x; ci < total; ci += gridDim.x) {
        // Map flat chunk index -> (deg bucket, chunk j within bucket).
        int deg = 0, j = 0;
        bool found = false;
#pragma unroll
        for (int d = 0; d < ND; ++d) {
            const int ch = (c[d] + RPC - 1) / RPC;
            if (!found && ci < base[d] + ch) { deg = d; j = ci - base[d]; found = true; }
        }
        const int nrows = min(RPC, c[deg] - j * RPC);

        if (t < RPC) rows_s[t] = (t < nrows) ? list[deg * NROWS + j * RPC + t] : -1;
        __syncthreads();

        // Build feat[f][r] for the RPC rows. All branches block-uniform
        // except t<NFB. Atom part: thread t = channel f (t in [0,256)).
#pragma unroll
        for (int r = 0; r < RPC; ++r) {
            const int row = rows_s[r];
            if (row >= 0) {
                const int rb = row & ~(NA - 1);        // b*NA
                const int* er = edges + row * ND;
                float v = atoms[(size_t)row * NFA + t];
#pragma unroll
                for (int d = 0; d < ND; ++d) {
                    const int e = er[d];
                    if (e != -1) v += atoms[((size_t)(rb + e)) * NFA + t];
                }
                feat[t * RPC + r] = v;
                if (t < NFB) {
                    const float* br = bonds + (size_t)row * (ND * NFB) + t;
                    feat[(NFA + t) * RPC + r] =
                        br[0] + br[NFB] + br[2 * NFB] + br[3 * NFB] + br[4 * NFB];
                }
            }
        }
        __syncthreads();

        // acc[r] over channels c=t. W reads coalesced across threads,
        // each loaded value reused RPC times.
        float acc[RPC];
        const float bv = bias[deg * NC + t];
#pragma unroll
        for (int r = 0; r < RPC; ++r) acc[r] = bv;

        const float* Wd = W + (size_t)deg * (NF * NC) + t;
#pragma unroll 8
        for (int f = 0; f < NF; ++f) {
            const float w = Wd[(size_t)f * NC];
            const float4 fv = *reinterpret_cast<const float4*>(&feat[f * RPC]);
            acc[0] = fmaf(fv.x, w, acc[0]);
            acc[1] = fmaf(fv.y, w, acc[1]);
            acc[2] = fmaf(fv.z, w, acc[2]);
            acc[3] = fmaf(fv.w, w, acc[3]);
        }

#pragma unroll
        for (int r = 0; r < RPC; ++r) {
            const int row = rows_s[r];
            if (row >= 0) out[(size_t)row * NC + t] = fmaxf(acc[r], 0.f);
        }
        __syncthreads();   // before next iteration overwrites feat/rows_s
    }
}

// ---------------------------------------------------------------------------
extern "C" void kernel_launch(void* const* d_in, const int* in_sizes, int n_in,
                              void* d_out, int out_size, void* d_ws, size_t ws_size,
                              hipStream_t stream) {
    const float* atoms = (const float*)d_in[0];
    const float* bonds = (const float*)d_in[1];
    const int*   edges = (const int*)  d_in[2];
    const float* W     = (const float*)d_in[3];
    const float* bias  = (const float*)d_in[4];
    float*       out   = (float*)d_out;

    const size_t need = 64 + (size_t)ND * NROWS * sizeof(int);  // ~656 KB
    if (d_ws == nullptr || ws_size < need) {
        // Workspace too small: previous verified single-kernel path.
        ngh_kernel<<<dim3(NROWS), dim3(NC), 0, stream>>>(atoms, bonds, edges, W, bias, out);
        return;
    }

    int* cnt  = (int*)d_ws;                    // 5 counters (64B reserved)
    int* list = (int*)((char*)d_ws + 64);      // 5 lists of NROWS ints

    hipMemsetAsync(cnt, 0, 64, stream);        // capturable memset node
    scan_zero_kernel<<<dim3(NROWS / RPB), dim3(256), 0, stream>>>(edges, out, cnt, list);
    gather_mm_kernel<<<dim3(1024), dim3(256), 0, stream>>>(atoms, bonds, edges, W, bias, out, cnt, list);
}